// Round 15
// baseline (115.806 us; speedup 1.0000x reference)
//
#include <hip/hip_runtime.h>

#define IN_CH 64
#define OUT_CH 128
#define HW 128
#define KTAPS 9
#define ROWB 16384             // bytes per staged row image: 128 w * 64 ic * 2B

typedef __bf16 bf16x8 __attribute__((ext_vector_type(8)));
typedef float f32x16 __attribute__((ext_vector_type(16)));
typedef float f32x4 __attribute__((ext_vector_type(4)));

// fp32 -> bf16 round-to-nearest-even (data has no NaN/Inf) — prep use
__device__ __forceinline__ unsigned f2bf(float f) {
    unsigned u = __builtin_bit_cast(unsigned, f);
    return (u + 0x7FFFu + ((u >> 16) & 1u)) >> 16;
}

// HW packed f32x2 -> bf16x2 (RNE), 1 instruction (no builtin on gfx950)
__device__ __forceinline__ unsigned cvt_pk_bf16(float lo, float hi) {
    unsigned r;
    asm("v_cvt_pk_bf16_f32 %0, %1, %2" : "=v"(r) : "v"(lo), "v"(hi));
    return r;   // [15:0]=bf16(lo), [31:16]=bf16(hi)
}

// 16B-granule XOR swizzle keyed by row (3 bits -> byte-addr bits 4..6).
__device__ __forceinline__ int swz(int r) { return ((r ^ (r >> 3)) & 7) << 4; }

// W (OIHW fp32) -> Wl in wave-fragment order (PROVEN R9-R14):
// 16B chunk index = (p*9 + t)*512 + (m*4 + ks)*64 + lane
// Chunk content: 8 bf16 of A[oc = p*64+m*32+(lane&31)][ic = ks*16+(lane>>5)*8 ..+8].
__global__ void wprep_kernel(const float* __restrict__ W, unsigned short* __restrict__ Wl) {
    int i = blockIdx.x * blockDim.x + threadIdx.x;   // 73728 bf16 elements
    if (i >= OUT_CH * IN_CH * KTAPS) return;
    int p  = i / 36864;
    int r  = i % 36864;
    int t  = r >> 12;          // 0..8
    int r2 = r & 4095;
    int m  = r2 >> 11;
    int ks = (r2 >> 9) & 3;
    int l  = (r2 >> 3) & 63;
    int e  = r2 & 7;
    int oc = p * 64 + m * 32 + (l & 31);
    int ic = ks * 16 + (l >> 5) * 8 + e;
    int kh = t / 3, kw = t % 3;
    Wl[i] = (unsigned short)f2bf(W[((oc * IN_CH + ic) * 3 + kh) * 3 + kw]);
}

// Persistent h-chain conv: 512 blocks (exactly 2/CU, one cohort). Block walks
// 4 output rows h = hb + 8j of one image n. Because dilation=8, consecutive
// tiles share 2 of 3 input rows: a 4-slot LDS ring stages only ONE new row
// per tile. Stores/staging of tile j overlap other waves' K-loops — breaking
// the cohort-wide phase correlation that pinned MfmaUtil at ~17%.
__global__ __launch_bounds__(512, 4) void conv_kernel_f(
    const float* __restrict__ x, const unsigned short* __restrict__ Wl,
    const float* __restrict__ bias, float* __restrict__ y)
{
    __shared__ __align__(16) unsigned char xs[4 * ROWB];   // 64 KiB ring -> 2 blocks/CU

    int bid = blockIdx.x;                       // 512 blocks
    int n   = (bid & 7) | (((bid >> 8) & 1) << 3);   // same-n blocks share an XCD (round-robin)
    int rem = (bid >> 3) & 31;                  // 32 h-chains per image
    int hb  = (rem & 7) + ((rem >> 3) << 5);    // chain base: {0..7}+{0,32,64,96}
    int tid = threadIdx.x;
    int wid = tid >> 6, lane = tid & 63;

    // wave roles (proven R9-R14): wr = oc quarter, wc = w half
    int wr = wid >> 1, wc = wid & 1;
    int l31 = lane & 31, lhi = lane >> 5;
    int p = wr >> 1, m = wr & 1;

    const bf16x8* Ab = reinterpret_cast<const bf16x8*>(Wl)
                     + p * (9 * 512) + m * 256 + lane;

    // hoist bias: the 16 oc values this thread stores are tile-invariant
    float bv[16];
    #pragma unroll
    for (int reg = 0; reg < 16; ++reg)
        bv[reg] = bias[wr * 32 + (reg & 3) + 8 * (reg >> 2) + 4 * lhi];

    // stage one x-row (fp32 -> bf16, swizzled) into ring slot; 1 group/thread:
    // (w4 = tid&31, ic4 = tid>>5): 4 float4 loads, 8 cvt_pk, 4 b64 writes.
    auto STAGE = [&](int slot, int srow) {
        int w4 = tid & 31, ic4 = tid >> 5;
        const float* xp = x + (((n * IN_CH + ic4 * 4) * HW + srow) * HW + w4 * 4);
        f32x4 v[4];
        #pragma unroll
        for (int j = 0; j < 4; ++j)
            v[j] = *reinterpret_cast<const f32x4*>(xp + j * (HW * HW));
        #pragma unroll
        for (int j2 = 0; j2 < 4; ++j2) {
            int w = w4 * 4 + j2;
            uint2 pk;
            pk.x = cvt_pk_bf16(v[0][j2], v[1][j2]);
            pk.y = cvt_pk_bf16(v[2][j2], v[3][j2]);
            *reinterpret_cast<uint2*>(xs + slot * ROWB + ((w * 128 + ic4 * 8) ^ swz(w))) = pk;
        }
    };

    // prologue: slots 0,1,2 = x-rows hb-8, hb, hb+8
    STAGE(0, (hb + 120) & 127);
    STAGE(1, hb);
    STAGE(2, (hb + 8) & 127);
    __syncthreads();

    f32x16 acc[2];

    #pragma unroll
    for (int j = 0; j < 4; ++j) {              // tile j: output row hb + 8j
        // stage tile j+1's new row into slot (j+3)&3 (== (j-1)&3, freed by the
        // tile-(j-1) barrier; disjoint from tile j's read slots j, j+1, j+2)
        if (j < 3) STAGE((j + 3) & 3, (hb + 8 * j + 16) & 127);

        #pragma unroll
        for (int bq = 0; bq < 2; ++bq)
            #pragma unroll
            for (int r = 0; r < 16; ++r) acc[bq][r] = 0.0f;

        #pragma unroll
        for (int t = 0; t < 9; ++t) {
            bf16x8 aCur[4];
            #pragma unroll
            for (int ks = 0; ks < 4; ++ks) aCur[ks] = Ab[t * 512 + ks * 64];

            int kh = t / 3, kw = t % 3;
            int sbase = ((j + kh) & 3) * ROWB;               // ring slot for this tap
            int xc0 = (wc * 64 + l31 + 8 * kw - 8) & 127;    // circular column
            int xc1 = (xc0 + 32) & 127;
            int b0base = sbase + xc0 * 128 + lhi * 16, s0 = swz(xc0);
            int b1base = sbase + xc1 * 128 + lhi * 16, s1 = swz(xc1);
            #pragma unroll
            for (int ks = 0; ks < 4; ++ks) {   // K=16 per MFMA, 64 ic per tap
                bf16x8 b0 = *reinterpret_cast<const bf16x8*>(xs + ((b0base + ks * 32) ^ s0));
                bf16x8 b1 = *reinterpret_cast<const bf16x8*>(xs + ((b1base + ks * 32) ^ s1));
                acc[0] = __builtin_amdgcn_mfma_f32_32x32x16_bf16(aCur[ks], b0, acc[0], 0, 0, 0);
                acc[1] = __builtin_amdgcn_mfma_f32_32x32x16_bf16(aCur[ks], b1, acc[1], 0, 0, 0);
            }
        }

        // epilogue: stores overlap other waves' compute (no cohort-wide burst)
        int outbase = (n * OUT_CH) * HW * HW + (hb + 8 * j) * HW;
        #pragma unroll
        for (int bq = 0; bq < 2; ++bq) {
            int wcol = wc * 64 + bq * 32 + l31;
            #pragma unroll
            for (int reg = 0; reg < 16; ++reg) {
                int oc = wr * 32 + (reg & 3) + 8 * (reg >> 2) + 4 * lhi;
                y[outbase + oc * HW * HW + wcol] = acc[bq][reg] + bv[reg];
            }
        }

        __syncthreads();   // tile boundary: staged row visible, read slots freed
    }
}

extern "C" void kernel_launch(void* const* d_in, const int* in_sizes, int n_in,
                              void* d_out, int out_size, void* d_ws, size_t ws_size,
                              hipStream_t stream) {
    const float* x = (const float*)d_in[0];
    const float* W = (const float*)d_in[1];
    const float* b = (const float*)d_in[2];
    float* y = (float*)d_out;

    unsigned short* Wl = (unsigned short*)d_ws;   // 147456 B

    hipLaunchKernelGGL(wprep_kernel, dim3((OUT_CH * IN_CH * KTAPS + 255) / 256), dim3(256), 0, stream, W, Wl);
    hipLaunchKernelGGL(conv_kernel_f, dim3(512), dim3(512), 0, stream, x, Wl, b, y);
}

// Round 16
// 71.668 us; speedup vs baseline: 1.6159x; 1.6159x over previous
//
#include <hip/hip_runtime.h>

#define IN_CH 64
#define OUT_CH 128
#define HW 128
#define KTAPS 9
#define ROWB 16384             // bytes per staged row image: 128 w * 64 ic * 2B

typedef __bf16 bf16x8 __attribute__((ext_vector_type(8)));
typedef float f32x16 __attribute__((ext_vector_type(16)));
typedef float f32x4 __attribute__((ext_vector_type(4)));

// fp32 -> bf16 round-to-nearest-even (data has no NaN/Inf) — prep use
__device__ __forceinline__ unsigned f2bf(float f) {
    unsigned u = __builtin_bit_cast(unsigned, f);
    return (u + 0x7FFFu + ((u >> 16) & 1u)) >> 16;
}

// HW packed f32x2 -> bf16x2 (RNE), 1 instruction (no builtin on gfx950)
__device__ __forceinline__ unsigned cvt_pk_bf16(float lo, float hi) {
    unsigned r;
    asm("v_cvt_pk_bf16_f32 %0, %1, %2" : "=v"(r) : "v"(lo), "v"(hi));
    return r;   // [15:0]=bf16(lo), [31:16]=bf16(hi)
}

// 16B-granule XOR swizzle keyed by row (3 bits -> byte-addr bits 4..6).
__device__ __forceinline__ int swz(int r) { return ((r ^ (r >> 3)) & 7) << 4; }

// W (OIHW fp32) -> Wl in wave-fragment order (PROVEN R9-R14):
// 16B chunk index = (p*9 + t)*512 + (m*4 + ks)*64 + lane
// Chunk content: 8 bf16 of A[oc = p*64+m*32+(lane&31)][ic = ks*16+(lane>>5)*8 ..+8].
__global__ void wprep_kernel(const float* __restrict__ W, unsigned short* __restrict__ Wl) {
    int i = blockIdx.x * blockDim.x + threadIdx.x;   // 73728 bf16 elements
    if (i >= OUT_CH * IN_CH * KTAPS) return;
    int p  = i / 36864;
    int r  = i % 36864;
    int t  = r >> 12;          // 0..8
    int r2 = r & 4095;
    int m  = r2 >> 11;
    int ks = (r2 >> 9) & 3;
    int l  = (r2 >> 3) & 63;
    int e  = r2 & 7;
    int oc = p * 64 + m * 32 + (l & 31);
    int ic = ks * 16 + (l >> 5) * 8 + e;
    int kh = t / 3, kw = t % 3;
    Wl[i] = (unsigned short)f2bf(W[((oc * IN_CH + ic) * 3 + kh) * 3 + kw]);
}

// Fused conv (R14 skeleton + T14 row-pipelined staging): 512 threads / 8 thin
// waves (32oc x 64w, acc=32) per (n,h). The 3 staged x-rows are loaded,
// converted and written ONE ROW AT A TIME, with row r+1's global loads issued
// before the taps that consume row r — HBM/L2 latency hides under MFMAs.
// Taps are kh-major so tap-triplet g needs only slot g.
__global__ __launch_bounds__(512, 4) void conv_kernel_f(
    const float* __restrict__ x, const unsigned short* __restrict__ Wl,
    const float* __restrict__ bias, float* __restrict__ y)
{
    __shared__ __align__(16) unsigned char xsB[3 * ROWB];   // 48 KiB -> 3 blocks/CU

    int bid = blockIdx.x;
    int sb  = (bid & 7) * 256 + (bid >> 3);   // XCD-contiguous h ranges (bijective: 2048 = 8*256)
    int n = sb >> 7, h = sb & 127;
    int tid = threadIdx.x;
    int wid = tid >> 6, lane = tid & 63;

    // wave roles: wr = oc quarter (32 rows), wc = w half (64 cols)
    int wr = wid >> 1, wc = wid & 1;
    int l31 = lane & 31, lhi = lane >> 5;
    int p = wr >> 1, m = wr & 1;

    const bf16x8* Ab = reinterpret_cast<const bf16x8*>(Wl)
                     + p * (9 * 512) + m * 256 + lane;

    // staging role: one (ic4, w4) quarter-column group per thread per row
    int w4 = tid & 31, ic4 = tid >> 5;
    const float* xg = x + ((n * IN_CH + ic4 * 4) * HW) * HW + w4 * 4;

    // issue the 4 global loads of one x-row (kept in regs across a tap-triplet)
    auto LOADROW = [&](int kh, f32x4 v[4]) {
        int srow = (h + kh * 8 + 120) & 127;   // h-8 + 8*kh (mod 128)
        const float* xp = xg + srow * HW;
        #pragma unroll
        for (int j = 0; j < 4; ++j)
            v[j] = *reinterpret_cast<const f32x4*>(xp + j * (HW * HW));
    };
    // convert + swizzled write of that row into its LDS slot
    auto WRITEROW = [&](int kh, const f32x4 v[4]) {
        #pragma unroll
        for (int j2 = 0; j2 < 4; ++j2) {
            int c = w4 * 4 + j2;
            uint2 pk;
            pk.x = cvt_pk_bf16(v[0][j2], v[1][j2]);
            pk.y = cvt_pk_bf16(v[2][j2], v[3][j2]);
            *reinterpret_cast<uint2*>(xsB + kh * ROWB + ((c * 128 + ic4 * 8) ^ swz(c))) = pk;
        }
    };

    f32x16 acc[2];
    #pragma unroll
    for (int bq = 0; bq < 2; ++bq)
        #pragma unroll
        for (int r = 0; r < 16; ++r) acc[bq][r] = 0.0f;

    // one tap-triplet (kh = slot): 3 taps x {4 A-loads, 8 B ds_reads, 8 MFMAs}
    auto TAPS = [&](int kh) {
        #pragma unroll
        for (int kw = 0; kw < 3; ++kw) {
            int t = kh * 3 + kw;
            bf16x8 aCur[4];
            #pragma unroll
            for (int ks = 0; ks < 4; ++ks) aCur[ks] = Ab[t * 512 + ks * 64];
            int xc0 = (wc * 64 + l31 + 8 * kw - 8) & 127;   // circular column
            int xc1 = (xc0 + 32) & 127;
            int b0base = kh * ROWB + xc0 * 128 + lhi * 16, s0 = swz(xc0);
            int b1base = kh * ROWB + xc1 * 128 + lhi * 16, s1 = swz(xc1);
            bf16x8 b[8];
            #pragma unroll
            for (int ks = 0; ks < 4; ++ks) {
                b[ks]     = *reinterpret_cast<const bf16x8*>(xsB + ((b0base + ks * 32) ^ s0));
                b[4 + ks] = *reinterpret_cast<const bf16x8*>(xsB + ((b1base + ks * 32) ^ s1));
            }
            __builtin_amdgcn_s_setprio(1);
            #pragma unroll
            for (int ks = 0; ks < 4; ++ks) {
                acc[0] = __builtin_amdgcn_mfma_f32_32x32x16_bf16(aCur[ks], b[ks],     acc[0], 0, 0, 0);
                acc[1] = __builtin_amdgcn_mfma_f32_32x32x16_bf16(aCur[ks], b[4 + ks], acc[1], 0, 0, 0);
            }
            __builtin_amdgcn_s_setprio(0);
        }
    };

    // ---- 3-phase pipeline: row r+1 loads fly under tap-triplet r ----
    f32x4 v0[4], v1[4];
    LOADROW(0, v0);
    WRITEROW(0, v0);           // row0 exposure is unavoidable (1/3 of old cost)
    __syncthreads();           // slot0 ready

    LOADROW(1, v1);            // issue row1 loads NOW (hide under taps 0-2)
    __builtin_amdgcn_sched_barrier(0);   // pin issue point (compiler sinks loads)
    TAPS(0);
    WRITEROW(1, v1);
    __syncthreads();           // slot1 ready

    LOADROW(2, v0);            // issue row2 loads (hide under taps 3-5)
    __builtin_amdgcn_sched_barrier(0);
    TAPS(1);
    WRITEROW(2, v0);
    __syncthreads();           // slot2 ready

    TAPS(2);

    // ---- epilogue: bias + store. D: col=l31(w), row=(reg&3)+8*(reg>>2)+4*lhi ----
    int outbase = (n * OUT_CH) * HW * HW + h * HW;
    #pragma unroll
    for (int bq = 0; bq < 2; ++bq) {
        int wcol = wc * 64 + bq * 32 + l31;
        #pragma unroll
        for (int reg = 0; reg < 16; ++reg) {
            int oc = wr * 32 + (reg & 3) + 8 * (reg >> 2) + 4 * lhi;
            y[outbase + oc * HW * HW + wcol] = acc[bq][reg] + bias[oc];
        }
    }
}

extern "C" void kernel_launch(void* const* d_in, const int* in_sizes, int n_in,
                              void* d_out, int out_size, void* d_ws, size_t ws_size,
                              hipStream_t stream) {
    const float* x = (const float*)d_in[0];
    const float* W = (const float*)d_in[1];
    const float* b = (const float*)d_in[2];
    float* y = (float*)d_out;

    unsigned short* Wl = (unsigned short*)d_ws;   // 147456 B

    hipLaunchKernelGGL(wprep_kernel, dim3((OUT_CH * IN_CH * KTAPS + 255) / 256), dim3(256), 0, stream, W, Wl);
    hipLaunchKernelGGL(conv_kernel_f, dim3(16 * HW), dim3(512), 0, stream, x, Wl, b, y);
}

// Round 17
// 68.535 us; speedup vs baseline: 1.6897x; 1.0457x over previous
//
#include <hip/hip_runtime.h>

#define IN_CH 64
#define OUT_CH 128
#define HW 128
#define KTAPS 9
#define ROWB 16384             // bytes per staged row image: 128 w * 64 ic * 2B

typedef __bf16 bf16x8 __attribute__((ext_vector_type(8)));
typedef float f32x16 __attribute__((ext_vector_type(16)));
typedef float f32x4 __attribute__((ext_vector_type(4)));

// fp32 -> bf16 round-to-nearest-even (data has no NaN/Inf) — prep use
__device__ __forceinline__ unsigned f2bf(float f) {
    unsigned u = __builtin_bit_cast(unsigned, f);
    return (u + 0x7FFFu + ((u >> 16) & 1u)) >> 16;
}

// HW packed f32x2 -> bf16x2 (RNE), 1 instruction (no builtin on gfx950)
__device__ __forceinline__ unsigned cvt_pk_bf16(float lo, float hi) {
    unsigned r;
    asm("v_cvt_pk_bf16_f32 %0, %1, %2" : "=v"(r) : "v"(lo), "v"(hi));
    return r;   // [15:0]=bf16(lo), [31:16]=bf16(hi)
}

// 16B-granule XOR swizzle keyed by row (3 bits -> byte-addr bits 4..6).
__device__ __forceinline__ int swz(int r) { return ((r ^ (r >> 3)) & 7) << 4; }

// W (OIHW fp32) -> Wl in wave-fragment order (PROVEN R9-R16):
// 16B chunk index = (p*9 + t)*512 + (m*4 + ks)*64 + lane
// Chunk content: 8 bf16 of A[oc = p*64+m*32+(lane&31)][ic = ks*16+(lane>>5)*8 ..+8].
__global__ void wprep_kernel(const float* __restrict__ W, unsigned short* __restrict__ Wl) {
    int i = blockIdx.x * blockDim.x + threadIdx.x;   // 73728 bf16 elements
    if (i >= OUT_CH * IN_CH * KTAPS) return;
    int p  = i / 36864;
    int r  = i % 36864;
    int t  = r >> 12;          // 0..8
    int r2 = r & 4095;
    int m  = r2 >> 11;
    int ks = (r2 >> 9) & 3;
    int l  = (r2 >> 3) & 63;
    int e  = r2 & 7;
    int oc = p * 64 + m * 32 + (l & 31);
    int ic = ks * 16 + (l >> 5) * 8 + e;
    int kh = t / 3, kw = t % 3;
    Wl[i] = (unsigned short)f2bf(W[((oc * IN_CH + ic) * 3 + kh) * 3 + kw]);
}

// Fused conv (R14 skeleton, B-reuse doubled): 512 threads / 8 waves per (n,h);
// wave = 64oc x 32w (wr = oc half, wc = w quarter). Per tap: 8 A-chunks from
// one contiguous 8KB L2/L1-resident slice, FOUR B ds_read_b128 (each feeding
// TWO MFMAs), 8 MFMAs. B LDS traffic halves vs the 32oc x 64w decomposition
// (1.21 GB -> 0.60 GB chip-wide) — attacking the largest measured pipe.
__global__ __launch_bounds__(512, 5) void conv_kernel_f(
    const float* __restrict__ x, const unsigned short* __restrict__ Wl,
    const float* __restrict__ bias, float* __restrict__ y)
{
    __shared__ __align__(16) unsigned char xsB[3 * ROWB];   // 48 KiB

    int bid = blockIdx.x;
    int sb  = (bid & 7) * 256 + (bid >> 3);   // XCD-contiguous h ranges (bijective: 2048 = 8*256)
    int n = sb >> 7, h = sb & 127;
    int tid = threadIdx.x;
    int wid = tid >> 6, lane = tid & 63;

    // wave roles: wr = oc half (64 rows), wc = w quarter (32 cols)
    int wr = wid >> 2, wc = wid & 3;
    int l31 = lane & 31, lhi = lane >> 5;

    // A chunk pointer (16B units): per tap the wave reads chunks
    // [t*512 + (m*4+ks)*64 + lane], an 8KB contiguous slice of half p = wr.
    const bf16x8* Ab = reinterpret_cast<const bf16x8*>(Wl) + wr * (9 * 512) + lane;

    // ---- stage 3 B-rows (h-8, h, h+8): 1536 quarter-groups (kh, ic4, w4),
    //      exactly 3 per thread; 4 float4 loads -> 8 cvt_pk -> 4 b64 writes.
    #pragma unroll
    for (int g = 0; g < 3; ++g) {
        int q   = g * 512 + tid;     // 0..1535
        int w4  = q & 31;
        int ic4 = (q >> 5) & 15;
        int kh  = q >> 9;
        int srow = (h + kh * 8 + 120) & 127;   // h-8, h, h+8 (mod 128)
        const float* xp = x + (((n * IN_CH + ic4 * 4) * HW + srow) * HW + w4 * 4);
        f32x4 v[4];
        #pragma unroll
        for (int j = 0; j < 4; ++j)
            v[j] = *reinterpret_cast<const f32x4*>(xp + j * (HW * HW));
        #pragma unroll
        for (int j2 = 0; j2 < 4; ++j2) {
            int w = w4 * 4 + j2;
            uint2 pk;
            pk.x = cvt_pk_bf16(v[0][j2], v[1][j2]);
            pk.y = cvt_pk_bf16(v[2][j2], v[3][j2]);
            *reinterpret_cast<uint2*>(xsB + kh * ROWB + ((w * 128 + ic4 * 8) ^ swz(w))) = pk;
        }
    }
    __syncthreads();   // the ONLY barrier

    f32x16 acc[2];     // acc[m]: oc rows wr*64 + m*32 .., cols wc*32 ..
    #pragma unroll
    for (int m = 0; m < 2; ++m)
        #pragma unroll
        for (int r = 0; r < 16; ++r) acc[m][r] = 0.0f;

    #pragma unroll
    for (int t = 0; t < 9; ++t) {
        // per-tap A fragments for both 32-row groups (8 lane-contiguous 1KB loads)
        bf16x8 a0[4], a1[4];
        #pragma unroll
        for (int ks = 0; ks < 4; ++ks) {
            a0[ks] = Ab[t * 512 + ks * 64];          // m = 0
            a1[ks] = Ab[t * 512 + (4 + ks) * 64];    // m = 1
        }
        int kh = t / 3, kw = t % 3;
        int xc = (wc * 32 + l31 + 8 * kw - 8) & 127;   // circular column
        int bbase = kh * ROWB + xc * 128 + lhi * 16, s = swz(xc);
        #pragma unroll
        for (int ks = 0; ks < 4; ++ks) {   // K=16 per MFMA; each B-frag feeds 2 MFMAs
            bf16x8 b = *reinterpret_cast<const bf16x8*>(xsB + ((bbase + ks * 32) ^ s));
            acc[0] = __builtin_amdgcn_mfma_f32_32x32x16_bf16(a0[ks], b, acc[0], 0, 0, 0);
            acc[1] = __builtin_amdgcn_mfma_f32_32x32x16_bf16(a1[ks], b, acc[1], 0, 0, 0);
        }
    }

    // ---- epilogue: bias + store. D: col=l31(w), row=(reg&3)+8*(reg>>2)+4*lhi ----
    int outbase = (n * OUT_CH) * HW * HW + h * HW;
    int wcol = wc * 32 + l31;
    #pragma unroll
    for (int m = 0; m < 2; ++m) {
        #pragma unroll
        for (int reg = 0; reg < 16; ++reg) {
            int oc = wr * 64 + m * 32 + (reg & 3) + 8 * (reg >> 2) + 4 * lhi;
            y[outbase + oc * HW * HW + wcol] = acc[m][reg] + bias[oc];
        }
    }
}

extern "C" void kernel_launch(void* const* d_in, const int* in_sizes, int n_in,
                              void* d_out, int out_size, void* d_ws, size_t ws_size,
                              hipStream_t stream) {
    const float* x = (const float*)d_in[0];
    const float* W = (const float*)d_in[1];
    const float* b = (const float*)d_in[2];
    float* y = (float*)d_out;

    unsigned short* Wl = (unsigned short*)d_ws;   // 147456 B

    hipLaunchKernelGGL(wprep_kernel, dim3((OUT_CH * IN_CH * KTAPS + 255) / 256), dim3(256), 0, stream, W, Wl);
    hipLaunchKernelGGL(conv_kernel_f, dim3(16 * HW), dim3(512), 0, stream, x, Wl, b, y);
}

// Round 18
// 61.221 us; speedup vs baseline: 1.8916x; 1.1195x over previous
//
#include <hip/hip_runtime.h>

#define IN_CH 64
#define OUT_CH 128
#define HW 128
#define KTAPS 9
#define ROWB 16384             // bytes per staged row image: 128 w * 64 ic * 2B

typedef __bf16 bf16x8 __attribute__((ext_vector_type(8)));
typedef float f32x16 __attribute__((ext_vector_type(16)));
typedef float f32x4 __attribute__((ext_vector_type(4)));

// fp32 -> bf16 round-to-nearest-even (data has no NaN/Inf) — prep use
__device__ __forceinline__ unsigned f2bf(float f) {
    unsigned u = __builtin_bit_cast(unsigned, f);
    return (u + 0x7FFFu + ((u >> 16) & 1u)) >> 16;
}

// HW packed f32x2 -> bf16x2 (RNE), 1 instruction (no builtin on gfx950)
__device__ __forceinline__ unsigned cvt_pk_bf16(float lo, float hi) {
    unsigned r;
    asm("v_cvt_pk_bf16_f32 %0, %1, %2" : "=v"(r) : "v"(lo), "v"(hi));
    return r;   // [15:0]=bf16(lo), [31:16]=bf16(hi)
}

// 16B-granule XOR swizzle keyed by row (3 bits -> byte-addr bits 4..6).
__device__ __forceinline__ int swz(int r) { return ((r ^ (r >> 3)) & 7) << 4; }

// W (OIHW fp32) -> Wl in wave-fragment order (PROVEN R9-R17):
// 16B chunk index = (p*9 + t)*512 + (m*4 + ks)*64 + lane
// Chunk content: 8 bf16 of A[oc = p*64+m*32+(lane&31)][ic = ks*16+(lane>>5)*8 ..+8].
__global__ void wprep_kernel(const float* __restrict__ W, unsigned short* __restrict__ Wl) {
    int i = blockIdx.x * blockDim.x + threadIdx.x;   // 73728 bf16 elements
    if (i >= OUT_CH * IN_CH * KTAPS) return;
    int p  = i / 36864;
    int r  = i % 36864;
    int t  = r >> 12;          // 0..8
    int r2 = r & 4095;
    int m  = r2 >> 11;
    int ks = (r2 >> 9) & 3;
    int l  = (r2 >> 3) & 63;
    int e  = r2 & 7;
    int oc = p * 64 + m * 32 + (l & 31);
    int ic = ks * 16 + (l >> 5) * 8 + e;
    int kh = t / 3, kw = t % 3;
    Wl[i] = (unsigned short)f2bf(W[((oc * IN_CH + ic) * 3 + kh) * 3 + kw]);
}

// Issue one tap's 4 A-fragment loads as volatile asm (compiler cannot sink
// them to their consumers). Base is per-lane; taps reached with imm offsets.
#define ISSUE_A(B0, B1, B2, B3, T) do {                                              \
    const char* _pp = (const char*)Ab + (T) * 8192;                                  \
    asm volatile("global_load_dwordx4 %0, %1, off"             : "=v"(B0) : "v"(_pp)); \
    asm volatile("global_load_dwordx4 %0, %1, off offset:1024" : "=v"(B1) : "v"(_pp)); \
    asm volatile("global_load_dwordx4 %0, %1, off offset:2048" : "=v"(B2) : "v"(_pp)); \
    asm volatile("global_load_dwordx4 %0, %1, off offset:3072" : "=v"(B3) : "v"(_pp)); \
} while (0)

// One tap's compute: counted vmcnt wait (never 0 until the last tap) +
// sched_barrier(0) fence (rule #18), then 8 swizzled ds_read_b128 + 8 MFMAs.
#define TAP_BODY(A0_, A1_, A2_, A3_, T, WAITSTR) do {                                \
    constexpr int _kh = (T) / 3, _kw = (T) % 3;                                      \
    int _xc0 = (wc * 64 + l31 + 8 * _kw - 8) & 127;                                  \
    int _xc1 = (_xc0 + 32) & 127;                                                    \
    int _b0 = _kh * ROWB + _xc0 * 128 + lhi * 16, _s0 = swz(_xc0);                   \
    int _b1 = _kh * ROWB + _xc1 * 128 + lhi * 16, _s1 = swz(_xc1);                   \
    asm volatile(WAITSTR);                                                           \
    __builtin_amdgcn_sched_barrier(0);                                               \
    const bf16x8 _A[4] = {A0_, A1_, A2_, A3_};                                       \
    _Pragma("unroll")                                                                \
    for (int ks = 0; ks < 4; ++ks) {                                                 \
        bf16x8 _vb0 = *reinterpret_cast<const bf16x8*>(xsB + ((_b0 + ks * 32) ^ _s0)); \
        bf16x8 _vb1 = *reinterpret_cast<const bf16x8*>(xsB + ((_b1 + ks * 32) ^ _s1)); \
        acc[0] = __builtin_amdgcn_mfma_f32_32x32x16_bf16(_A[ks], _vb0, acc[0], 0, 0, 0); \
        acc[1] = __builtin_amdgcn_mfma_f32_32x32x16_bf16(_A[ks], _vb1, acc[1], 0, 0, 0); \
    }                                                                                \
} while (0)

// Fused conv (session best, R14): 512 threads / 8 thin waves (32oc x 64w,
// acc=32) per (n,h); B staged once (cvt_pk, balanced, swizzled); A streamed
// from L2-resident Wl through an asm counted-vmcnt double-buffer pipeline.
__global__ __launch_bounds__(512, 5) void conv_kernel_f(
    const float* __restrict__ x, const unsigned short* __restrict__ Wl,
    const float* __restrict__ bias, float* __restrict__ y)
{
    __shared__ __align__(16) unsigned char xsB[3 * ROWB];   // 48 KiB -> 3 blocks/CU

    int bid = blockIdx.x;
    int sb  = (bid & 7) * 256 + (bid >> 3);   // XCD-contiguous h ranges (bijective: 2048 = 8*256)
    int n = sb >> 7, h = sb & 127;
    int tid = threadIdx.x;
    int wid = tid >> 6, lane = tid & 63;

    // wave roles: wr = oc quarter (32 rows), wc = w half (64 cols)
    int wr = wid >> 1, wc = wid & 1;
    int l31 = lane & 31, lhi = lane >> 5;
    int p = wr >> 1, m = wr & 1;

    // A chunk pointer (16B units): proven fragment order, quarter-selected.
    const bf16x8* Ab = reinterpret_cast<const bf16x8*>(Wl)
                     + p * (9 * 512) + m * 256 + lane;

    // tap-0 A loads issued FIRST (asm, cannot sink): fly under all of staging;
    // the staging barrier's vmcnt(0) drain guarantees they're ready for tap 0.
    bf16x8 aE0, aE1, aE2, aE3, aO0, aO1, aO2, aO3;
    ISSUE_A(aE0, aE1, aE2, aE3, 0);

    // ---- stage 3 B-rows (h-8, h, h+8): 1536 quarter-groups (kh, ic4, w4),
    //      exactly 3 per thread; 4 float4 loads -> 8 cvt_pk -> 4 b64 writes.
    #pragma unroll
    for (int g = 0; g < 3; ++g) {
        int q   = g * 512 + tid;     // 0..1535
        int w4  = q & 31;
        int ic4 = (q >> 5) & 15;
        int kh  = q >> 9;
        int srow = (h + kh * 8 + 120) & 127;   // h-8, h, h+8 (mod 128)
        const float* xp = x + (((n * IN_CH + ic4 * 4) * HW + srow) * HW + w4 * 4);
        f32x4 v[4];
        #pragma unroll
        for (int j = 0; j < 4; ++j)
            v[j] = *reinterpret_cast<const f32x4*>(xp + j * (HW * HW));
        #pragma unroll
        for (int j2 = 0; j2 < 4; ++j2) {
            int w = w4 * 4 + j2;
            uint2 pk;
            pk.x = cvt_pk_bf16(v[0][j2], v[1][j2]);
            pk.y = cvt_pk_bf16(v[2][j2], v[3][j2]);
            *reinterpret_cast<uint2*>(xsB + kh * ROWB + ((w * 128 + ic4 * 8) ^ swz(w))) = pk;
        }
    }
    __syncthreads();   // the ONLY barrier (drains staging + tap-0 A loads)

    f32x16 acc[2];
    #pragma unroll
    for (int bq = 0; bq < 2; ++bq)
        #pragma unroll
        for (int r = 0; r < 16; ++r) acc[bq][r] = 0.0f;

    // ---- K-loop: asm double-buffered A, counted vmcnt(4), one-tap lookahead.
    // Steady state keeps 4-8 loads in flight; never drains to 0 until t=8.
    ISSUE_A(aO0, aO1, aO2, aO3, 1);
    TAP_BODY(aE0, aE1, aE2, aE3, 0, "s_waitcnt vmcnt(4)");
    ISSUE_A(aE0, aE1, aE2, aE3, 2);
    TAP_BODY(aO0, aO1, aO2, aO3, 1, "s_waitcnt vmcnt(4)");
    ISSUE_A(aO0, aO1, aO2, aO3, 3);
    TAP_BODY(aE0, aE1, aE2, aE3, 2, "s_waitcnt vmcnt(4)");
    ISSUE_A(aE0, aE1, aE2, aE3, 4);
    TAP_BODY(aO0, aO1, aO2, aO3, 3, "s_waitcnt vmcnt(4)");
    ISSUE_A(aO0, aO1, aO2, aO3, 5);
    TAP_BODY(aE0, aE1, aE2, aE3, 4, "s_waitcnt vmcnt(4)");
    ISSUE_A(aE0, aE1, aE2, aE3, 6);
    TAP_BODY(aO0, aO1, aO2, aO3, 5, "s_waitcnt vmcnt(4)");
    ISSUE_A(aO0, aO1, aO2, aO3, 7);
    TAP_BODY(aE0, aE1, aE2, aE3, 6, "s_waitcnt vmcnt(4)");
    ISSUE_A(aE0, aE1, aE2, aE3, 8);
    TAP_BODY(aO0, aO1, aO2, aO3, 7, "s_waitcnt vmcnt(4)");
    TAP_BODY(aE0, aE1, aE2, aE3, 8, "s_waitcnt vmcnt(0)");

    // ---- epilogue: bias + store. D: col=l31(w), row=(reg&3)+8*(reg>>2)+4*lhi ----
    int outbase = (n * OUT_CH) * HW * HW + h * HW;
    #pragma unroll
    for (int bq = 0; bq < 2; ++bq) {
        int wcol = wc * 64 + bq * 32 + l31;
        #pragma unroll
        for (int reg = 0; reg < 16; ++reg) {
            int oc = wr * 32 + (reg & 3) + 8 * (reg >> 2) + 4 * lhi;
            y[outbase + oc * HW * HW + wcol] = acc[bq][reg] + bias[oc];
        }
    }
}

extern "C" void kernel_launch(void* const* d_in, const int* in_sizes, int n_in,
                              void* d_out, int out_size, void* d_ws, size_t ws_size,
                              hipStream_t stream) {
    const float* x = (const float*)d_in[0];
    const float* W = (const float*)d_in[1];
    const float* b = (const float*)d_in[2];
    float* y = (float*)d_out;

    unsigned short* Wl = (unsigned short*)d_ws;   // 147456 B

    hipLaunchKernelGGL(wprep_kernel, dim3((OUT_CH * IN_CH * KTAPS + 255) / 256), dim3(256), 0, stream, W, Wl);
    hipLaunchKernelGGL(conv_kernel_f, dim3(16 * HW), dim3(512), 0, stream, x, Wl, b, y);
}